// Round 3
// baseline (458.567 us; speedup 1.0000x reference)
//
#include <hip/hip_runtime.h>

// ---------------------------------------------------------------------------
// 2-layer GCN on MI355X.
//   gcn_conv(x,W,b):  hs = (x@W) * dinv[row]          (gemm_scale_kernel)
//                     agg[i] = hs[i] + sum_{s->i} hs[s]  (aggregate_kernel, CSR)
//                     out = agg * dinv[i] + b  (+relu)
// CSR over dst built once per call (count -> exclusive scan -> fill), reused
// by both layers. Self-loop handled by initializing acc with hs[node] and
// deg = in_count + 1.
// ---------------------------------------------------------------------------

__global__ void count_kernel(const int* __restrict__ dst, int E, int* __restrict__ cnt) {
    int i = blockIdx.x * blockDim.x + threadIdx.x;
    if (i < E) atomicAdd(&cnt[dst[i]], 1);
}

__global__ void dinv_kernel(const int* __restrict__ cnt, float* __restrict__ dinv, int n) {
    int i = blockIdx.x * blockDim.x + threadIdx.x;
    if (i < n) {
        float deg = (float)(cnt[i] + 1);   // +1 self-loop; always > 0
        dinv[i] = 1.0f / sqrtf(deg);
    }
}

// Single-block exclusive scan of cnt[0..n) -> rowptr[0..n]; rowptr[n] = E.
// Each of 1024 threads owns a contiguous chunk: serial sum, block scan of
// partials (shfl within wave, LDS across 16 waves), serial rewrite.
__global__ __launch_bounds__(1024) void scan_kernel(const int* __restrict__ cnt,
                                                    int* __restrict__ rowptr, int n) {
    const int T = 1024;
    int chunk = (n + T - 1) / T;
    int beg = threadIdx.x * chunk;
    int end = beg + chunk;
    if (beg > n) beg = n;
    if (end > n) end = n;

    int s = 0;
    for (int i = beg; i < end; ++i) s += cnt[i];

    int lane = threadIdx.x & 63;
    int wid  = threadIdx.x >> 6;
    int x = s;
    #pragma unroll
    for (int off = 1; off < 64; off <<= 1) {
        int y = __shfl_up(x, off);
        if (lane >= off) x += y;
    }
    __shared__ int wsum[16];
    if (lane == 63) wsum[wid] = x;
    __syncthreads();
    if (threadIdx.x < 16) {
        int v = wsum[threadIdx.x];
        #pragma unroll
        for (int off = 1; off < 16; off <<= 1) {
            int y = __shfl_up(v, off);
            if ((int)threadIdx.x >= off) v += y;
        }
        wsum[threadIdx.x] = v;
    }
    __syncthreads();
    int pre = ((wid > 0) ? wsum[wid - 1] : 0) + (x - s);  // exclusive prefix of this thread
    int run = pre;
    for (int i = beg; i < end; ++i) { rowptr[i] = run; run += cnt[i]; }
    if (threadIdx.x == T - 1) rowptr[n] = run;            // total = E
}

__global__ void fill_kernel(const int* __restrict__ src, const int* __restrict__ dst, int E,
                            const int* __restrict__ rowptr, int* __restrict__ cur,
                            int* __restrict__ csr) {
    int i = blockIdx.x * blockDim.x + threadIdx.x;
    if (i < E) {
        int d = dst[i];
        int pos = rowptr[d] + atomicAdd(&cur[d], 1);
        csr[pos] = src[i];
    }
}

// out[r, c] = dinv[r] * sum_k X[r,k] * W[k,c]   for c = lane (64 cols).
// Block = 4 waves; each wave computes 4 rows at once so each LDS read of W
// is reused by 4 FMAs. W staged in LDS ([K][64] row-major: lane-consecutive
// reads, 2 lanes/bank = conflict-free). Grid-stride over row groups.
template <int K>
__global__ __launch_bounds__(256) void gemm_scale_kernel(const float* __restrict__ X,
                                                         const float* __restrict__ W,
                                                         const float* __restrict__ dinv,
                                                         float* __restrict__ out, int n) {
    __shared__ float sW[K * 64];
    for (int idx = threadIdx.x; idx < K * 64; idx += 256) sW[idx] = W[idx];
    __syncthreads();

    const int lane = threadIdx.x & 63;
    const int wid  = threadIdx.x >> 6;
    const int groupStride = gridDim.x * 4;          // wave-groups per grid step

    for (int g = blockIdx.x * 4 + wid; g * 4 < n; g += groupStride) {
        int r0 = g * 4;
        if (r0 + 4 <= n) {
            const float4* x0 = reinterpret_cast<const float4*>(X + (size_t)(r0 + 0) * K);
            const float4* x1 = reinterpret_cast<const float4*>(X + (size_t)(r0 + 1) * K);
            const float4* x2 = reinterpret_cast<const float4*>(X + (size_t)(r0 + 2) * K);
            const float4* x3 = reinterpret_cast<const float4*>(X + (size_t)(r0 + 3) * K);
            float a0 = 0.f, a1 = 0.f, a2 = 0.f, a3 = 0.f;
            #pragma unroll
            for (int k4 = 0; k4 < K / 4; ++k4) {
                float4 v0 = x0[k4], v1 = x1[k4], v2 = x2[k4], v3 = x3[k4];
                const float* wp = &sW[(k4 * 4) * 64 + lane];
                float w0 = wp[0], w1 = wp[64], w2 = wp[128], w3 = wp[192];
                a0 = fmaf(v0.x, w0, a0); a0 = fmaf(v0.y, w1, a0);
                a0 = fmaf(v0.z, w2, a0); a0 = fmaf(v0.w, w3, a0);
                a1 = fmaf(v1.x, w0, a1); a1 = fmaf(v1.y, w1, a1);
                a1 = fmaf(v1.z, w2, a1); a1 = fmaf(v1.w, w3, a1);
                a2 = fmaf(v2.x, w0, a2); a2 = fmaf(v2.y, w1, a2);
                a2 = fmaf(v2.z, w2, a2); a2 = fmaf(v2.w, w3, a2);
                a3 = fmaf(v3.x, w0, a3); a3 = fmaf(v3.y, w1, a3);
                a3 = fmaf(v3.z, w2, a3); a3 = fmaf(v3.w, w3, a3);
            }
            out[(size_t)(r0 + 0) * 64 + lane] = a0 * dinv[r0 + 0];
            out[(size_t)(r0 + 1) * 64 + lane] = a1 * dinv[r0 + 1];
            out[(size_t)(r0 + 2) * 64 + lane] = a2 * dinv[r0 + 2];
            out[(size_t)(r0 + 3) * 64 + lane] = a3 * dinv[r0 + 3];
        } else {
            for (int r = r0; r < n; ++r) {
                const float* xr = X + (size_t)r * K;
                float a = 0.f;
                for (int k = 0; k < K; ++k) a = fmaf(xr[k], sW[k * 64 + lane], a);
                out[(size_t)r * 64 + lane] = a * dinv[r];
            }
        }
    }
}

// One wave per node; lane = column. acc starts with the self-loop term hs[node].
// Edge sources read wave-uniformly from CSR; each neighbor row gather is one
// coalesced 256 B request. 4-deep unroll keeps 4 gathers in flight.
template <bool RELU>
__global__ __launch_bounds__(256) void aggregate_kernel(const float* __restrict__ hs,
                                                        const int* __restrict__ rowptr,
                                                        const int* __restrict__ csr,
                                                        const float* __restrict__ dinv,
                                                        const float* __restrict__ bias,
                                                        float* __restrict__ out, int n) {
    const int lane = threadIdx.x & 63;
    const int wid  = threadIdx.x >> 6;
    int node = blockIdx.x * 4 + wid;
    if (node >= n) return;

    int beg = rowptr[node], end = rowptr[node + 1];
    float acc = hs[(size_t)node * 64 + lane];
    int e = beg;
    for (; e + 4 <= end; e += 4) {
        int s0 = csr[e + 0], s1 = csr[e + 1], s2 = csr[e + 2], s3 = csr[e + 3];
        float v0 = hs[(size_t)s0 * 64 + lane];
        float v1 = hs[(size_t)s1 * 64 + lane];
        float v2 = hs[(size_t)s2 * 64 + lane];
        float v3 = hs[(size_t)s3 * 64 + lane];
        acc += (v0 + v1) + (v2 + v3);
    }
    for (; e < end; ++e) acc += hs[(size_t)csr[e] * 64 + lane];

    float r = fmaf(acc, dinv[node], bias[lane]);
    if (RELU) r = fmaxf(r, 0.0f);
    out[(size_t)node * 64 + lane] = r;
}

extern "C" void kernel_launch(void* const* d_in, const int* in_sizes, int n_in,
                              void* d_out, int out_size, void* d_ws, size_t ws_size,
                              hipStream_t stream) {
    const float* x  = (const float*)d_in[0];
    const int*   ei = (const int*)d_in[1];   // [2, E] int32
    const float* W1 = (const float*)d_in[2]; // [128, 64]
    const float* b1 = (const float*)d_in[3]; // [64]
    const float* W2 = (const float*)d_in[4]; // [64, 64]
    const float* b2 = (const float*)d_in[5]; // [64]
    float* out = (float*)d_out;

    const int E = in_sizes[1] / 2;   // 1,600,000
    const int n = out_size / 64;     // 50,000

    // workspace carve (256 B aligned sections)
    char* wsp = (char*)d_ws;
    auto carve = [&](size_t bytes) {
        char* p = wsp;
        wsp += (bytes + 255) & ~(size_t)255;
        return p;
    };
    float* dinv   = (float*)carve((size_t)n * 4);
    int*   rowptr = (int*)  carve((size_t)(n + 1) * 4);
    int*   cnt    = (int*)  carve((size_t)n * 4);
    int*   csr    = (int*)  carve((size_t)E * 4);
    float* hbuf   = (float*)carve((size_t)n * 64 * 4);
    float* hsbuf  = (float*)carve((size_t)n * 64 * 4);

    const int* srcIdx = ei;
    const int* dstIdx = ei + E;

    // --- graph preprocessing (shared by both layers) ---
    hipMemsetAsync(cnt, 0, (size_t)n * 4, stream);
    count_kernel<<<(E + 255) / 256, 256, 0, stream>>>(dstIdx, E, cnt);
    dinv_kernel<<<(n + 255) / 256, 256, 0, stream>>>(cnt, dinv, n);
    scan_kernel<<<1, 1024, 0, stream>>>(cnt, rowptr, n);
    hipMemsetAsync(cnt, 0, (size_t)n * 4, stream);
    fill_kernel<<<(E + 255) / 256, 256, 0, stream>>>(srcIdx, dstIdx, E, rowptr, cnt, csr);

    // --- layer 1: relu(gcn_conv(x, W1, b1)) -> hbuf ---
    gemm_scale_kernel<128><<<1024, 256, 0, stream>>>(x, W1, dinv, hsbuf, n);
    aggregate_kernel<true><<<(n + 3) / 4, 256, 0, stream>>>(hsbuf, rowptr, csr, dinv, b1, hbuf, n);

    // --- layer 2: gcn_conv(hbuf, W2, b2) -> out ---
    gemm_scale_kernel<64><<<1024, 256, 0, stream>>>(hbuf, W2, dinv, hsbuf, n);
    aggregate_kernel<false><<<(n + 3) / 4, 256, 0, stream>>>(hsbuf, rowptr, csr, dinv, b2, out, n);
}

// Round 6
// 254.891 us; speedup vs baseline: 1.7991x; 1.7991x over previous
//
#include <hip/hip_runtime.h>

// ---------------------------------------------------------------------------
// 2-layer GCN on MI355X.
//   prep:   bucketed counting sort of edges by dst -> CSR + rowptr + dinv
//   layer:  hs = (x@W) * dinv[row]            (gemm_scale_kernel)
//           agg[i] = hs[i] + sum_{s->i} hs[s] (aggregate_kernel, CSR)
//           out = agg * dinv[i] + b (+relu)
// Bucket = 128 consecutive nodes (dst >> 7). Scatter writes (src,dst) pairs
// into per-bucket runs reserved per block -> write-combined (vs the old
// random 4B csr scatter that cost 102 MB of HBM writeback / 80 us).
// ---------------------------------------------------------------------------

#define NPB_SHIFT 7
#define NPB 128            // nodes per bucket
#define NBMAX 1024         // supports n <= 131072
#define EPB 4096           // edges per scatter block
#define KPB (EPB / 256)    // edges per thread in scatter block
#define EMAX 8192          // LDS csr staging capacity per bucket

__global__ __launch_bounds__(256) void bucket_count_kernel(const int* __restrict__ dst, int E,
                                                           int NB, int* __restrict__ bucketCnt) {
    __shared__ int cnt[NBMAX];
    for (int i = threadIdx.x; i < NB; i += 256) cnt[i] = 0;
    __syncthreads();
    int base = blockIdx.x * EPB;
    #pragma unroll
    for (int k = 0; k < KPB; ++k) {
        int i = base + k * 256 + threadIdx.x;
        if (i < E) atomicAdd(&cnt[dst[i] >> NPB_SHIFT], 1);
    }
    __syncthreads();
    for (int i = threadIdx.x; i < NB; i += 256) {
        int c = cnt[i];
        if (c) atomicAdd(&bucketCnt[i], c);
    }
}

// Single block: exclusive scan of bucketCnt[0..NB) -> bucketOff[0..NB]
// (bucketOff[NB] = E), and bucketCur = bucketOff.
__global__ __launch_bounds__(1024) void bucket_scan_kernel(const int* __restrict__ bucketCnt, int NB,
                                                           int* __restrict__ bucketOff,
                                                           int* __restrict__ bucketCur) {
    int t = threadIdx.x;
    int v = (t < NB) ? bucketCnt[t] : 0;
    int lane = t & 63, wid = t >> 6;
    int x = v;
    #pragma unroll
    for (int off = 1; off < 64; off <<= 1) {
        int y = __shfl_up(x, off);
        if (lane >= off) x += y;
    }
    __shared__ int ws[16];
    if (lane == 63) ws[wid] = x;
    __syncthreads();
    if (t < 16) {
        int s = ws[t];
        #pragma unroll
        for (int off = 1; off < 16; off <<= 1) {
            int y = __shfl_up(s, off);
            if (t >= off) s += y;
        }
        ws[t] = s;
    }
    __syncthreads();
    int incl = x + (wid ? ws[wid - 1] : 0);
    int excl = incl - v;
    if (t < NB) { bucketOff[t] = excl; bucketCur[t] = excl; }
    if (t == 1023) bucketOff[NB] = incl;   // total = E
}

// Scatter (src,dst) pairs into per-bucket runs. Per block: LDS histogram of
// its 4096 edges, one global atomicAdd per touched bucket to reserve a run,
// then LDS-offset scatter. Lines of `pairs` are written by one block within
// a short window -> L2 write-combining -> ~1x writeback.
__global__ __launch_bounds__(256) void bin_scatter_kernel(const int* __restrict__ src,
                                                          const int* __restrict__ dst, int E, int NB,
                                                          int* __restrict__ bucketCur,
                                                          int2* __restrict__ pairs) {
    __shared__ int cntA[NBMAX];
    __shared__ int baseB[NBMAX];
    for (int i = threadIdx.x; i < NB; i += 256) cntA[i] = 0;
    __syncthreads();
    int base = blockIdx.x * EPB;
    int s_[KPB], d_[KPB];
    #pragma unroll
    for (int k = 0; k < KPB; ++k) {
        int i = base + k * 256 + threadIdx.x;
        if (i < E) {
            s_[k] = src[i];
            d_[k] = dst[i];
            atomicAdd(&cntA[d_[k] >> NPB_SHIFT], 1);
        } else {
            d_[k] = -1;
        }
    }
    __syncthreads();
    for (int i = threadIdx.x; i < NB; i += 256) {
        int c = cntA[i];
        baseB[i] = c ? atomicAdd(&bucketCur[i], c) : 0;
        cntA[i] = 0;
    }
    __syncthreads();
    #pragma unroll
    for (int k = 0; k < KPB; ++k) {
        if (d_[k] >= 0) {
            int b = d_[k] >> NPB_SHIFT;
            int off = atomicAdd(&cntA[b], 1);
            pairs[baseB[b] + off] = make_int2(s_[k], d_[k]);
        }
    }
}

// One block per bucket: count per-node deg (LDS), wave-scan -> local rowptr,
// write rowptr/dinv, LDS-scatter src into CSR order, coalesced csr write.
__global__ __launch_bounds__(256) void build_csr_kernel(const int2* __restrict__ pairs,
                                                        const int* __restrict__ bucketOff,
                                                        int NB, int n, int E,
                                                        int* __restrict__ rowptr,
                                                        float* __restrict__ dinv,
                                                        int* __restrict__ csr) {
    __shared__ int deg[NPB];
    __shared__ int cur[NPB];
    __shared__ int rowL[NPB];
    __shared__ int lcsr[EMAX];
    int b = blockIdx.x;
    int nodeBase = b << NPB_SHIFT;
    int nNodes = min(NPB, n - nodeBase);
    int eBeg = bucketOff[b], eEnd = bucketOff[b + 1];
    int m = eEnd - eBeg;
    for (int i = threadIdx.x; i < NPB; i += 256) { deg[i] = 0; cur[i] = 0; }
    __syncthreads();
    for (int e = eBeg + threadIdx.x; e < eEnd; e += 256)
        atomicAdd(&deg[pairs[e].y - nodeBase], 1);
    __syncthreads();
    // exclusive scan of deg[0..NPB) by wave 0, 2 elements per lane
    if (threadIdx.x < 64) {
        int j0 = threadIdx.x * 2, j1 = j0 + 1;
        int d0 = deg[j0], d1 = deg[j1];
        int s = d0 + d1;
        int x = s;
        #pragma unroll
        for (int off = 1; off < 64; off <<= 1) {
            int y = __shfl_up(x, off);
            if ((int)threadIdx.x >= off) x += y;
        }
        int excl = x - s;
        rowL[j0] = excl;
        rowL[j1] = excl + d0;
    }
    __syncthreads();
    for (int j = threadIdx.x; j < nNodes; j += 256) {
        rowptr[nodeBase + j] = eBeg + rowL[j];
        dinv[nodeBase + j] = 1.0f / sqrtf((float)(deg[j] + 1));  // +1 self-loop
    }
    if (b == NB - 1 && threadIdx.x == 0) rowptr[n] = E;
    if (m <= EMAX) {
        for (int e = eBeg + threadIdx.x; e < eEnd; e += 256) {
            int2 p = pairs[e];
            int d = p.y - nodeBase;
            int off = atomicAdd(&cur[d], 1);
            lcsr[rowL[d] + off] = p.x;
        }
        __syncthreads();
        for (int i = threadIdx.x; i < m; i += 256) csr[eBeg + i] = lcsr[i];
    } else {  // overflow fallback (adversarial degree distribution): direct scatter
        for (int e = eBeg + threadIdx.x; e < eEnd; e += 256) {
            int2 p = pairs[e];
            int d = p.y - nodeBase;
            int off = atomicAdd(&cur[d], 1);
            csr[eBeg + rowL[d] + off] = p.x;
        }
    }
}

// out[r, c] = dinv[r] * sum_k X[r,k] * W[k,c]   for c = lane (64 cols).
template <int K>
__global__ __launch_bounds__(256) void gemm_scale_kernel(const float* __restrict__ X,
                                                         const float* __restrict__ W,
                                                         const float* __restrict__ dinv,
                                                         float* __restrict__ out, int n) {
    __shared__ float sW[K * 64];
    for (int idx = threadIdx.x; idx < K * 64; idx += 256) sW[idx] = W[idx];
    __syncthreads();

    const int lane = threadIdx.x & 63;
    const int wid  = threadIdx.x >> 6;
    const int groupStride = gridDim.x * 4;

    for (int g = blockIdx.x * 4 + wid; g * 4 < n; g += groupStride) {
        int r0 = g * 4;
        if (r0 + 4 <= n) {
            const float4* x0 = reinterpret_cast<const float4*>(X + (size_t)(r0 + 0) * K);
            const float4* x1 = reinterpret_cast<const float4*>(X + (size_t)(r0 + 1) * K);
            const float4* x2 = reinterpret_cast<const float4*>(X + (size_t)(r0 + 2) * K);
            const float4* x3 = reinterpret_cast<const float4*>(X + (size_t)(r0 + 3) * K);
            float a0 = 0.f, a1 = 0.f, a2 = 0.f, a3 = 0.f;
            #pragma unroll
            for (int k4 = 0; k4 < K / 4; ++k4) {
                float4 v0 = x0[k4], v1 = x1[k4], v2 = x2[k4], v3 = x3[k4];
                const float* wp = &sW[(k4 * 4) * 64 + lane];
                float w0 = wp[0], w1 = wp[64], w2 = wp[128], w3 = wp[192];
                a0 = fmaf(v0.x, w0, a0); a0 = fmaf(v0.y, w1, a0);
                a0 = fmaf(v0.z, w2, a0); a0 = fmaf(v0.w, w3, a0);
                a1 = fmaf(v1.x, w0, a1); a1 = fmaf(v1.y, w1, a1);
                a1 = fmaf(v1.z, w2, a1); a1 = fmaf(v1.w, w3, a1);
                a2 = fmaf(v2.x, w0, a2); a2 = fmaf(v2.y, w1, a2);
                a2 = fmaf(v2.z, w2, a2); a2 = fmaf(v2.w, w3, a2);
                a3 = fmaf(v3.x, w0, a3); a3 = fmaf(v3.y, w1, a3);
                a3 = fmaf(v3.z, w2, a3); a3 = fmaf(v3.w, w3, a3);
            }
            out[(size_t)(r0 + 0) * 64 + lane] = a0 * dinv[r0 + 0];
            out[(size_t)(r0 + 1) * 64 + lane] = a1 * dinv[r0 + 1];
            out[(size_t)(r0 + 2) * 64 + lane] = a2 * dinv[r0 + 2];
            out[(size_t)(r0 + 3) * 64 + lane] = a3 * dinv[r0 + 3];
        } else {
            for (int r = r0; r < n; ++r) {
                const float* xr = X + (size_t)r * K;
                float a = 0.f;
                for (int k = 0; k < K; ++k) a = fmaf(xr[k], sW[k * 64 + lane], a);
                out[(size_t)r * 64 + lane] = a * dinv[r];
            }
        }
    }
}

// One wave per node; lane = column. acc starts with the self-loop term hs[node].
template <bool RELU>
__global__ __launch_bounds__(256) void aggregate_kernel(const float* __restrict__ hs,
                                                        const int* __restrict__ rowptr,
                                                        const int* __restrict__ csr,
                                                        const float* __restrict__ dinv,
                                                        const float* __restrict__ bias,
                                                        float* __restrict__ out, int n) {
    const int lane = threadIdx.x & 63;
    const int wid  = threadIdx.x >> 6;
    int node = blockIdx.x * 4 + wid;
    if (node >= n) return;

    int beg = rowptr[node], end = rowptr[node + 1];
    float acc = hs[(size_t)node * 64 + lane];
    int e = beg;
    for (; e + 4 <= end; e += 4) {
        int s0 = csr[e + 0], s1 = csr[e + 1], s2 = csr[e + 2], s3 = csr[e + 3];
        float v0 = hs[(size_t)s0 * 64 + lane];
        float v1 = hs[(size_t)s1 * 64 + lane];
        float v2 = hs[(size_t)s2 * 64 + lane];
        float v3 = hs[(size_t)s3 * 64 + lane];
        acc += (v0 + v1) + (v2 + v3);
    }
    for (; e < end; ++e) acc += hs[(size_t)csr[e] * 64 + lane];

    float r = fmaf(acc, dinv[node], bias[lane]);
    if (RELU) r = fmaxf(r, 0.0f);
    out[(size_t)node * 64 + lane] = r;
}

extern "C" void kernel_launch(void* const* d_in, const int* in_sizes, int n_in,
                              void* d_out, int out_size, void* d_ws, size_t ws_size,
                              hipStream_t stream) {
    const float* x  = (const float*)d_in[0];
    const int*   ei = (const int*)d_in[1];   // [2, E] int32
    const float* W1 = (const float*)d_in[2]; // [128, 64]
    const float* b1 = (const float*)d_in[3]; // [64]
    const float* W2 = (const float*)d_in[4]; // [64, 64]
    const float* b2 = (const float*)d_in[5]; // [64]
    float* out = (float*)d_out;

    const int E = in_sizes[1] / 2;   // 1,600,000
    const int n = out_size / 64;     // 50,000
    const int NB = (n + NPB - 1) >> NPB_SHIFT;   // 391 buckets

    // workspace carve (256 B aligned). pairs overlaps hbuf/hsbuf: prep is
    // finished before layer 1 writes them (same-stream ordering).
    char* wsp = (char*)d_ws;
    auto carve = [&](size_t bytes) {
        char* p = wsp;
        wsp += (bytes + 255) & ~(size_t)255;
        return p;
    };
    float* dinv      = (float*)carve((size_t)n * 4);
    int*   rowptr    = (int*)  carve((size_t)(n + 1) * 4);
    int*   bucketCnt = (int*)  carve((size_t)NBMAX * 4);
    int*   bucketOff = (int*)  carve((size_t)(NBMAX + 1) * 4);
    int*   bucketCur = (int*)  carve((size_t)NBMAX * 4);
    int*   csr       = (int*)  carve((size_t)E * 4);
    size_t featBytes = (size_t)n * 64 * 4;
    size_t bigBytes  = (size_t)E * 8 > 2 * featBytes ? (size_t)E * 8 : 2 * featBytes;
    char*  big       = (char*)carve(bigBytes);
    int2*  pairs     = (int2*)big;
    float* hbuf      = (float*)big;                 // overlaps pairs (dead by then)
    float* hsbuf     = (float*)(big + featBytes);

    const int* srcIdx = ei;
    const int* dstIdx = ei + E;
    const int scatterBlocks = (E + EPB - 1) / EPB;  // 391

    // --- prep: bucketed counting sort -> csr, rowptr, dinv ---
    hipMemsetAsync(bucketCnt, 0, (size_t)NBMAX * 4, stream);
    bucket_count_kernel<<<scatterBlocks, 256, 0, stream>>>(dstIdx, E, NB, bucketCnt);
    bucket_scan_kernel<<<1, 1024, 0, stream>>>(bucketCnt, NB, bucketOff, bucketCur);
    bin_scatter_kernel<<<scatterBlocks, 256, 0, stream>>>(srcIdx, dstIdx, E, NB, bucketCur, pairs);
    build_csr_kernel<<<NB, 256, 0, stream>>>(pairs, bucketOff, NB, n, E, rowptr, dinv, csr);

    // --- layer 1: relu(gcn_conv(x, W1, b1)) -> hbuf ---
    gemm_scale_kernel<128><<<1024, 256, 0, stream>>>(x, W1, dinv, hsbuf, n);
    aggregate_kernel<true><<<(n + 3) / 4, 256, 0, stream>>>(hsbuf, rowptr, csr, dinv, b1, hbuf, n);

    // --- layer 2: gcn_conv(hbuf, W2, b2) -> out ---
    gemm_scale_kernel<64><<<1024, 256, 0, stream>>>(hbuf, W2, dinv, hsbuf, n);
    aggregate_kernel<false><<<(n + 3) / 4, 256, 0, stream>>>(hsbuf, rowptr, csr, dinv, b2, out, n);
}